// Round 1
// baseline (950.890 us; speedup 1.0000x reference)
//
#include <hip/hip_runtime.h>
#include <math.h>

#define NN 512
#define HH 4
#define EE 256
#define NHH (NN*HH)
#define EPSF 1e-6f

__device__ __forceinline__ float elu1(float t) {
    // elu(t) + 1 : t>0 -> t+1 ; else exp(t)
    return t > 0.0f ? (t + 1.0f) : expf(t);
}

// Phase 1: projections + feature map + Zi update + normalizer.
// One block handles R=8 (n,h) rows; 256 threads, thread e owns output feature e.
__global__ __launch_bounds__(256) void la_phase1(
    const float* __restrict__ x, const float* __restrict__ Zi,
    const float* __restrict__ Wq, const float* __restrict__ bq,
    const float* __restrict__ Wk, const float* __restrict__ bk,
    const float* __restrict__ Wv, const float* __restrict__ bv,
    float* __restrict__ zi_new,
    float* __restrict__ kqz_ws, float* __restrict__ kk_ws, float* __restrict__ v_ws)
{
    constexpr int R = 8;
    const int e = threadIdx.x;
    const int row0 = blockIdx.x * R;

    __shared__ float xs[R][EE];
    __shared__ float red[4][R];

    #pragma unroll
    for (int r = 0; r < R; ++r)
        xs[r][e] = x[(size_t)(row0 + r) * EE + e];
    __syncthreads();

    const float4* Wq4 = (const float4*)Wq + (size_t)e * (EE/4);
    const float4* Wk4 = (const float4*)Wk + (size_t)e * (EE/4);
    const float4* Wv4 = (const float4*)Wv + (size_t)e * (EE/4);

    float accq[R], acck[R], accv[R];
    #pragma unroll
    for (int r = 0; r < R; ++r) { accq[r] = 0.f; acck[r] = 0.f; accv[r] = 0.f; }

    for (int j = 0; j < EE/4; ++j) {
        float4 wq = Wq4[j];
        float4 wk = Wk4[j];
        float4 wv = Wv4[j];
        #pragma unroll
        for (int r = 0; r < R; ++r) {
            float4 xr = ((const float4*)xs[r])[j];   // LDS b128 broadcast
            accq[r] += xr.x*wq.x + xr.y*wq.y + xr.z*wq.z + xr.w*wq.w;
            acck[r] += xr.x*wk.x + xr.y*wk.y + xr.z*wk.z + xr.w*wk.w;
            accv[r] += xr.x*wv.x + xr.y*wv.y + xr.z*wv.z + xr.w*wv.w;
        }
    }

    const float bqe = bq[e], bke = bk[e], bve = bv[e];
    const int lane = e & 63, wid = e >> 6;
    float kq[R], zn[R];

    #pragma unroll
    for (int r = 0; r < R; ++r) {
        kq[r]  = elu1(accq[r] + bqe);
        float kkr = elu1(acck[r] + bke);
        acck[r] = kkr;                 // now holds kk
        accv[r] = accv[r] + bve;       // now holds v
        size_t idx = (size_t)(row0 + r) * EE + e;
        zn[r] = Zi[idx] + kkr;
        zi_new[idx] = zn[r];
    }

    // Z = 1/(kq . Zi_new + eps), one per row; block-wide reduce over e.
    #pragma unroll
    for (int r = 0; r < R; ++r) {
        float p = kq[r] * zn[r];
        #pragma unroll
        for (int off = 32; off > 0; off >>= 1) p += __shfl_xor(p, off, 64);
        if (lane == 0) red[wid][r] = p;
    }
    __syncthreads();

    #pragma unroll
    for (int r = 0; r < R; ++r) {
        float s = red[0][r] + red[1][r] + red[2][r] + red[3][r];
        float Z = 1.0f / (s + EPSF);
        size_t idx = (size_t)(row0 + r) * EE + e;
        kqz_ws[idx] = kq[r] * Z;   // fold Z into kq so phase 2 needs no scalar
        kk_ws[idx]  = acck[r];
        v_ws[idx]   = accv[r];
    }
}

// Phase 2: stream Si once. One block per (n,h). 256 threads = 4 d-groups x 64
// float4-column lanes. Fused: Si_new store + V accumulation + out projection.
__global__ __launch_bounds__(256) void la_phase2(
    const float* __restrict__ Si,
    const float* __restrict__ kqz_ws, const float* __restrict__ kk_ws,
    const float* __restrict__ v_ws,
    const float* __restrict__ Wo, const float* __restrict__ bo,
    float* __restrict__ out, float* __restrict__ si_new)
{
    const int nh  = blockIdx.x;
    const int tid = threadIdx.x;
    const int mt  = tid & 63;   // which float4 column group (m = mt*4 .. mt*4+3)
    const int dg  = tid >> 6;   // d-group 0..3

    __shared__ float kks[EE];
    __shared__ float kqs[EE];
    __shared__ float Vp[4][EE];
    __shared__ float Vs[EE];

    kks[tid] = kk_ws[(size_t)nh * EE + tid];
    kqs[tid] = kqz_ws[(size_t)nh * EE + tid];
    __syncthreads();

    const float4* Si4 = (const float4*)Si     + (size_t)nh * (EE*(EE/4));
    float4*       So4 = (float4*)si_new       + (size_t)nh * (EE*(EE/4));
    const float4  v4  = ((const float4*)v_ws)[(size_t)nh * (EE/4) + mt];

    float vx = 0.f, vy = 0.f, vz = 0.f, vw = 0.f;
    #pragma unroll 4
    for (int d = dg; d < EE; d += 4) {
        const float kkd = kks[d];
        const float kqd = kqs[d];
        float4 s = Si4[(size_t)d * (EE/4) + mt];
        s.x = fmaf(kkd, v4.x, s.x);
        s.y = fmaf(kkd, v4.y, s.y);
        s.z = fmaf(kkd, v4.z, s.z);
        s.w = fmaf(kkd, v4.w, s.w);
        So4[(size_t)d * (EE/4) + mt] = s;
        vx = fmaf(kqd, s.x, vx);
        vy = fmaf(kqd, s.y, vy);
        vz = fmaf(kqd, s.z, vz);
        vw = fmaf(kqd, s.w, vw);
    }

    Vp[dg][mt*4 + 0] = vx;
    Vp[dg][mt*4 + 1] = vy;
    Vp[dg][mt*4 + 2] = vz;
    Vp[dg][mt*4 + 3] = vw;
    __syncthreads();
    Vs[tid] = Vp[0][tid] + Vp[1][tid] + Vp[2][tid] + Vp[3][tid];
    __syncthreads();

    // out[e] = V . Wo[e,:] + bo[e]   (Wo is 256 KB -> L2-resident)
    const float4* Wo4 = (const float4*)Wo + (size_t)tid * (EE/4);
    const float4* Vs4 = (const float4*)Vs;
    float acc = bo[tid];
    #pragma unroll 8
    for (int j = 0; j < EE/4; ++j) {
        float4 w  = Wo4[j];
        float4 vv = Vs4[j];
        acc += w.x*vv.x + w.y*vv.y + w.z*vv.z + w.w*vv.w;
    }
    out[(size_t)nh * EE + tid] = acc;
}

extern "C" void kernel_launch(void* const* d_in, const int* in_sizes, int n_in,
                              void* d_out, int out_size, void* d_ws, size_t ws_size,
                              hipStream_t stream) {
    const float* x  = (const float*)d_in[0];
    const float* Si = (const float*)d_in[1];
    const float* Zi = (const float*)d_in[2];
    const float* Wq = (const float*)d_in[3];
    const float* bq = (const float*)d_in[4];
    const float* Wk = (const float*)d_in[5];
    const float* bk = (const float*)d_in[6];
    const float* Wv = (const float*)d_in[7];
    const float* bv = (const float*)d_in[8];
    const float* Wo = (const float*)d_in[9];
    const float* bo = (const float*)d_in[10];

    float* out_p   = (float*)d_out;                              // (N,H,E)
    float* si_new  = out_p  + (size_t)NHH * EE;                  // (N,H,E,E)
    float* zi_new  = si_new + (size_t)NHH * EE * EE;             // (N,H,E)

    float* kqz_ws = (float*)d_ws;                // (NH,E) kq * Z
    float* kk_ws  = kqz_ws + (size_t)NHH * EE;   // (NH,E)
    float* v_ws   = kk_ws  + (size_t)NHH * EE;   // (NH,E)

    la_phase1<<<NHH/8, 256, 0, stream>>>(x, Zi, Wq, bq, Wk, bk, Wv, bv,
                                         zi_new, kqz_ws, kk_ws, v_ws);
    la_phase2<<<NHH, 256, 0, stream>>>(Si, kqz_ws, kk_ws, v_ws, Wo, bo,
                                       out_p, si_new);
}